// Round 2
// baseline (298.714 us; speedup 1.0000x reference)
//
#include <hip/hip_runtime.h>
#include <hip/hip_bf16.h>

#define BSZ 4
#define SEQ 2048
#define DIM 1024

typedef __attribute__((ext_vector_type(8))) short bf16x8;
typedef __attribute__((ext_vector_type(4))) float floatx4;

typedef __attribute__((address_space(3))) unsigned short lds_ushort;
typedef __attribute__((address_space(1))) const unsigned short g_ushort;

__device__ __forceinline__ void load16(const unsigned short* g, unsigned short* l) {
  // async global->LDS DMA, 16 B per lane; LDS dest = wave-uniform base + lane*16
  __builtin_amdgcn_global_load_lds((g_ushort*)g, (lds_ushort*)l, 16, 0, 0);
}

__device__ __forceinline__ unsigned short f2bf(float x) {
  union { float f; unsigned int u; } v; v.f = x;
  unsigned int r = v.u + 0x7fffu + ((v.u >> 16) & 1u);
  return (unsigned short)(r >> 16);
}

template <typename T> __device__ __forceinline__ void store_c(T* p, float v);
template <> __device__ __forceinline__ void store_c<float>(float* p, float v) { *p = v; }
template <> __device__ __forceinline__ void store_c<unsigned short>(unsigned short* p, float v) { *p = f2bf(v); }

// ---------------- cast fp32 -> bf16 (vectorized) ----------------
__global__ __launch_bounds__(256) void cast_e(const float* __restrict__ in,
                                              unsigned short* __restrict__ out, int n) {
  int i = (blockIdx.x * 256 + threadIdx.x) * 4;
  if (i >= n) return;
  float4 v = *(const float4*)(in + i);
  ushort4 o;
  o.x = f2bf(v.x); o.y = f2bf(v.y); o.z = f2bf(v.z); o.w = f2bf(v.w);
  *(ushort4*)(out + i) = o;
}

// ---------------- transpose + cast weights ----------------
__global__ __launch_bounds__(256) void transpose_w(const float* __restrict__ Wq,
                                                   const float* __restrict__ Wk,
                                                   const float* __restrict__ Wv,
                                                   unsigned short* __restrict__ WtQK,
                                                   unsigned short* __restrict__ WtV) {
  __shared__ float tile[32][33];
  int z = blockIdx.z;
  const float* W = (z == 0) ? Wq : (z == 1) ? Wk : Wv;
  unsigned short* dst = (z == 2) ? WtV : WtQK;
  int row_off = (z == 1) ? 1024 : 0;
  int n0 = blockIdx.x * 32, k0 = blockIdx.y * 32;
  int tx = threadIdx.x, ty = threadIdx.y;
  for (int r = ty; r < 32; r += 8)
    tile[r][tx] = W[(size_t)(k0 + r) * DIM + n0 + tx];
  __syncthreads();
  for (int r = ty; r < 32; r += 8)
    dst[(size_t)(row_off + n0 + r) * DIM + k0 + tx] = f2bf(tile[tx][r]);
}

// ---------------- NT bf16 MFMA GEMM (m97-class: global_load_lds staging) ----------------
// C[m][n] = scale * sum_k A[m][k] * B[n][k]
// CAUSAL: 0 = none, 1 = skip tiles with n0 > m0 (scores), 2 = Keff = min(K, m0+128) (PV)
template <typename OutT, int CAUSAL>
__global__ __launch_bounds__(256) void gemm_nt(
    const unsigned short* __restrict__ A, int lda, long long strideA,
    const unsigned short* __restrict__ B, int ldb, long long strideB,
    OutT* __restrict__ C, int ldc, long long strideC,
    int Kdim, float scale) {
  int m0 = blockIdx.y * 128;
  int n0 = blockIdx.x * 128;
  if (CAUSAL == 1 && n0 > m0) return;
  int Keff = (CAUSAL == 2) ? min(Kdim, m0 + 128) : Kdim;
  A += (long long)blockIdx.z * strideA;
  B += (long long)blockIdx.z * strideB;
  C += (long long)blockIdx.z * strideC;

  // UNPADDED: global_load_lds requires lane-contiguous LDS (wave base + lane*16B)
  __shared__ __align__(16) unsigned short As[128][64];
  __shared__ __align__(16) unsigned short Bs[128][64];

  int tid = threadIdx.x;
  int lane = tid & 63;
  int wid = tid >> 6;
  int wm = (wid >> 1) * 64, wn = (wid & 1) * 64;
  int lr = lane & 15, lq = lane >> 4;

  // staging geometry: wave wid, iter i covers flat ushort [wid*512 + i*2048, +512)
  int srow = wid * 8 + (lane >> 3);      // + i*32
  int skc = (lane & 7) * 8;

  floatx4 acc[4][4] = {};

  for (int k0 = 0; k0 < Keff; k0 += 64) {
    __syncthreads();  // prev iter's ds_reads done before DMA overwrites LDS
#pragma unroll
    for (int i = 0; i < 4; i++) {
      int row = srow + i * 32;
      int uoff = wid * 512 + i * 2048;   // wave-uniform ushort offset
      load16(A + (size_t)(m0 + row) * lda + k0 + skc, &As[0][0] + uoff);
      load16(B + (size_t)(n0 + row) * ldb + k0 + skc, &Bs[0][0] + uoff);
    }
    __syncthreads();  // drains vmcnt -> LDS data visible
#pragma unroll
    for (int kk = 0; kk < 64; kk += 32) {
      bf16x8 af[4], bfr[4];
      int kl = kk + lq * 8;
#pragma unroll
      for (int i = 0; i < 4; i++) af[i] = *(const bf16x8*)&As[wm + i * 16 + lr][kl];
#pragma unroll
      for (int j = 0; j < 4; j++) bfr[j] = *(const bf16x8*)&Bs[wn + j * 16 + lr][kl];
#pragma unroll
      for (int i = 0; i < 4; i++)
#pragma unroll
        for (int j = 0; j < 4; j++)
          acc[i][j] = __builtin_amdgcn_mfma_f32_16x16x32_bf16(af[i], bfr[j], acc[i][j], 0, 0, 0);
    }
  }

  // C/D layout (verified m89/m91): col = lane&15, row = (lane>>4)*4 + reg
#pragma unroll
  for (int i = 0; i < 4; i++) {
    int rbase = m0 + wm + i * 16 + lq * 4;
#pragma unroll
    for (int j = 0; j < 4; j++) {
      int col = n0 + wn + j * 16 + lr;
#pragma unroll
      for (int r = 0; r < 4; r++)
        store_c(&C[(size_t)(rbase + r) * ldc + col], acc[i][j][r] * scale);
    }
  }
}

// ---------------- causal row softmax: fp32 scores -> bf16 probs ----------------
__global__ __launch_bounds__(256) void softmax_causal(const float* __restrict__ scores,
                                                      unsigned short* __restrict__ probs) {
  int q = blockIdx.x;
  int b = blockIdx.y;
  const float* srow = scores + ((size_t)b * SEQ + q) * SEQ;
  unsigned short* prow = probs + ((size_t)b * SEQ + q) * SEQ;
  int valid = q + 1;
  int tid = threadIdx.x;
  __shared__ float red[4];

  float mx = -INFINITY;
  for (int i = tid; i < valid; i += 256) mx = fmaxf(mx, srow[i]);
  for (int off = 32; off; off >>= 1) mx = fmaxf(mx, __shfl_xor(mx, off, 64));
  if ((tid & 63) == 0) red[tid >> 6] = mx;
  __syncthreads();
  mx = fmaxf(fmaxf(red[0], red[1]), fmaxf(red[2], red[3]));
  __syncthreads();

  float sum = 0.0f;
  for (int i = tid; i < valid; i += 256) sum += __expf(srow[i] - mx);
  for (int off = 32; off; off >>= 1) sum += __shfl_xor(sum, off, 64);
  if ((tid & 63) == 0) red[tid >> 6] = sum;
  __syncthreads();
  sum = red[0] + red[1] + red[2] + red[3];
  float inv = 1.0f / sum;

  for (int i = tid; i < SEQ; i += 256) {
    float v = (i < valid) ? __expf(srow[i] - mx) * inv : 0.0f;
    prow[i] = f2bf(v);
  }
}

extern "C" void kernel_launch(void* const* d_in, const int* in_sizes, int n_in,
                              void* d_out, int out_size, void* d_ws, size_t ws_size,
                              hipStream_t stream) {
  const float* E  = (const float*)d_in[0];
  const float* Wq = (const float*)d_in[1];
  const float* Wk = (const float*)d_in[2];
  const float* Wv = (const float*)d_in[3];
  float* out = (float*)d_out;

  char* ws = (char*)d_ws;
  size_t off = 0;
  auto alloc = [&](size_t bytes) {
    void* p = ws + off;
    off += (bytes + 255) & ~(size_t)255;
    return p;
  };
  const size_t M_ALL = (size_t)BSZ * SEQ;
  unsigned short* Ebf  = (unsigned short*)alloc(M_ALL * DIM * 2);
  unsigned short* WtQK = (unsigned short*)alloc((size_t)2 * DIM * DIM * 2);
  unsigned short* WtV  = (unsigned short*)alloc((size_t)DIM * DIM * 2);
  unsigned short* QK   = (unsigned short*)alloc(M_ALL * 2 * DIM * 2);
  unsigned short* Vt   = (unsigned short*)alloc((size_t)DIM * M_ALL * 2);
  float*          Sc   = (float*)alloc((size_t)BSZ * SEQ * SEQ * 4);
  unsigned short* Pr   = (unsigned short*)alloc((size_t)BSZ * SEQ * SEQ * 2);

  int nE = (int)(M_ALL * DIM);
  cast_e<<<dim3(nE / (256 * 4)), dim3(256), 0, stream>>>(E, Ebf, nE);
  transpose_w<<<dim3(32, 32, 3), dim3(32, 8), 0, stream>>>(Wq, Wk, Wv, WtQK, WtV);

  gemm_nt<unsigned short, 0><<<dim3(16, 64, 1), dim3(256), 0, stream>>>(
      Ebf, DIM, 0, WtQK, DIM, 0, QK, 2 * DIM, 0, DIM, 1.0f);

  gemm_nt<unsigned short, 0><<<dim3(64, 8, 1), dim3(256), 0, stream>>>(
      WtV, DIM, 0, Ebf, DIM, 0, Vt, (int)M_ALL, 0, DIM, 1.0f);

  gemm_nt<float, 1><<<dim3(16, 16, BSZ), dim3(256), 0, stream>>>(
      QK, 2 * DIM, (long long)SEQ * 2 * DIM,
      QK + DIM, 2 * DIM, (long long)SEQ * 2 * DIM,
      Sc, SEQ, (long long)SEQ * SEQ,
      DIM, 0.03125f);

  softmax_causal<<<dim3(SEQ, BSZ), dim3(256), 0, stream>>>(Sc, Pr);

  gemm_nt<float, 2><<<dim3(8, 16, BSZ), dim3(256), 0, stream>>>(
      Pr, SEQ, (long long)SEQ * SEQ,
      Vt, (int)M_ALL, (long long)SEQ,
      out, DIM, (long long)SEQ * DIM,
      SEQ, 1.0f);
}

// Round 3
// 280.611 us; speedup vs baseline: 1.0645x; 1.0645x over previous
//
#include <hip/hip_runtime.h>
#include <hip/hip_bf16.h>

#define BSZ 4
#define SEQ 2048
#define DIM 1024

typedef __attribute__((ext_vector_type(8))) short bf16x8;
typedef __attribute__((ext_vector_type(4))) float floatx4;

typedef __attribute__((address_space(3))) unsigned short lds_ushort;
typedef __attribute__((address_space(1))) const unsigned short g_ushort;

__device__ __forceinline__ void load16(const unsigned short* g, unsigned short* l) {
  // async global->LDS DMA, 16 B per lane; LDS dest = wave-uniform base + lane*16
  __builtin_amdgcn_global_load_lds((g_ushort*)g, (lds_ushort*)l, 16, 0, 0);
}

__device__ __forceinline__ unsigned short f2bf(float x) {
  union { float f; unsigned int u; } v; v.f = x;
  unsigned int r = v.u + 0x7fffu + ((v.u >> 16) & 1u);
  return (unsigned short)(r >> 16);
}

template <typename T> __device__ __forceinline__ void store_c(T* p, float v);
template <> __device__ __forceinline__ void store_c<float>(float* p, float v) { *p = v; }
template <> __device__ __forceinline__ void store_c<unsigned short>(unsigned short* p, float v) { *p = f2bf(v); }

// ---------------- cast fp32 -> bf16 (vectorized) ----------------
__global__ __launch_bounds__(256) void cast_e(const float* __restrict__ in,
                                              unsigned short* __restrict__ out, int n) {
  int i = (blockIdx.x * 256 + threadIdx.x) * 4;
  if (i >= n) return;
  float4 v = *(const float4*)(in + i);
  ushort4 o;
  o.x = f2bf(v.x); o.y = f2bf(v.y); o.z = f2bf(v.z); o.w = f2bf(v.w);
  *(ushort4*)(out + i) = o;
}

// ---------------- transpose + cast weights ----------------
__global__ __launch_bounds__(256) void transpose_w(const float* __restrict__ Wq,
                                                   const float* __restrict__ Wk,
                                                   const float* __restrict__ Wv,
                                                   unsigned short* __restrict__ WtQK,
                                                   unsigned short* __restrict__ WtV) {
  __shared__ float tile[32][33];
  int z = blockIdx.z;
  const float* W = (z == 0) ? Wq : (z == 1) ? Wk : Wv;
  unsigned short* dst = (z == 2) ? WtV : WtQK;
  int row_off = (z == 1) ? 1024 : 0;
  int n0 = blockIdx.x * 32, k0 = blockIdx.y * 32;
  int tx = threadIdx.x, ty = threadIdx.y;
  for (int r = ty; r < 32; r += 8)
    tile[r][tx] = W[(size_t)(k0 + r) * DIM + n0 + tx];
  __syncthreads();
  for (int r = ty; r < 32; r += 8)
    dst[(size_t)(row_off + n0 + r) * DIM + k0 + tx] = f2bf(tile[tx][r]);
}

// ---------------- NT bf16 MFMA GEMM (DMA staging + XOR granule swizzle) ----------------
// C[m][n] = scale * sum_k A[m][k] * B[n][k]
// LDS layout: granule g' of row r holds data granule g = g' ^ (r & 7).
//   - DMA staging is lane-contiguous (required); lane fetches the granule that
//     belongs at its LDS slot:  skc = ((lane&7) ^ (lane>>3)) * 8.
//   - Fragment reads un-permute: column = ((kl>>3) ^ (lr&7)) * 8.  The 16 rows
//     of a ds_read_b128 then span 8 distinct granules -> 2-way bank alias (free).
// CAUSAL: 0 = none, 1 = skip tiles with n0 > m0 (scores), 2 = Keff = min(K, m0+128) (PV)
template <typename OutT, int CAUSAL>
__global__ __launch_bounds__(256) void gemm_nt(
    const unsigned short* __restrict__ A, int lda, long long strideA,
    const unsigned short* __restrict__ B, int ldb, long long strideB,
    OutT* __restrict__ C, int ldc, long long strideC,
    int Kdim, float scale) {
  int m0 = blockIdx.y * 128;
  int n0 = blockIdx.x * 128;
  if (CAUSAL == 1 && n0 > m0) return;
  int Keff = (CAUSAL == 2) ? min(Kdim, m0 + 128) : Kdim;
  A += (long long)blockIdx.z * strideA;
  B += (long long)blockIdx.z * strideB;
  C += (long long)blockIdx.z * strideC;

  __shared__ __align__(16) unsigned short As[128][64];
  __shared__ __align__(16) unsigned short Bs[128][64];

  int tid = threadIdx.x;
  int lane = tid & 63;
  int wid = tid >> 6;
  int wm = (wid >> 1) * 64, wn = (wid & 1) * 64;
  int lr = lane & 15, lq = lane >> 4;
  int swz = lr & 7;

  // staging: wave wid, iter i covers rows [wid*8 + i*32, +8), lane l -> row +(l>>3)
  int srow = wid * 8 + (lane >> 3);                    // + i*32
  int skc = ((lane & 7) ^ (lane >> 3)) * 8;            // XOR-swizzled source granule

  floatx4 acc[4][4] = {};

  for (int k0 = 0; k0 < Keff; k0 += 64) {
    __syncthreads();  // prev iter's ds_reads done before DMA overwrites LDS
#pragma unroll
    for (int i = 0; i < 4; i++) {
      int row = srow + i * 32;
      int uoff = wid * 512 + i * 2048;   // wave-uniform ushort offset
      load16(A + (size_t)(m0 + row) * lda + k0 + skc, &As[0][0] + uoff);
      load16(B + (size_t)(n0 + row) * ldb + k0 + skc, &Bs[0][0] + uoff);
    }
    __syncthreads();  // drains vmcnt -> LDS data visible
#pragma unroll
    for (int kk = 0; kk < 64; kk += 32) {
      bf16x8 af[4], bfr[4];
      int kl = kk + lq * 8;
      int col = ((kl >> 3) ^ swz) << 3;  // un-swizzle
#pragma unroll
      for (int i = 0; i < 4; i++) af[i] = *(const bf16x8*)&As[wm + i * 16 + lr][col];
#pragma unroll
      for (int j = 0; j < 4; j++) bfr[j] = *(const bf16x8*)&Bs[wn + j * 16 + lr][col];
#pragma unroll
      for (int i = 0; i < 4; i++)
#pragma unroll
        for (int j = 0; j < 4; j++)
          acc[i][j] = __builtin_amdgcn_mfma_f32_16x16x32_bf16(af[i], bfr[j], acc[i][j], 0, 0, 0);
    }
  }

  // C/D layout (verified m89/m91): col = lane&15, row = (lane>>4)*4 + reg
#pragma unroll
  for (int i = 0; i < 4; i++) {
    int rbase = m0 + wm + i * 16 + lq * 4;
#pragma unroll
    for (int j = 0; j < 4; j++) {
      int col = n0 + wn + j * 16 + lr;
#pragma unroll
      for (int r = 0; r < 4; r++)
        store_c(&C[(size_t)(rbase + r) * ldc + col], acc[i][j][r] * scale);
    }
  }
}

// ---------------- causal row softmax: fp32 scores -> bf16 probs ----------------
__global__ __launch_bounds__(256) void softmax_causal(const float* __restrict__ scores,
                                                      unsigned short* __restrict__ probs) {
  int q = blockIdx.x;
  int b = blockIdx.y;
  const float* srow = scores + ((size_t)b * SEQ + q) * SEQ;
  unsigned short* prow = probs + ((size_t)b * SEQ + q) * SEQ;
  int valid = q + 1;
  int tid = threadIdx.x;
  __shared__ float red[4];

  float mx = -INFINITY;
  for (int i = tid; i < valid; i += 256) mx = fmaxf(mx, srow[i]);
  for (int off = 32; off; off >>= 1) mx = fmaxf(mx, __shfl_xor(mx, off, 64));
  if ((tid & 63) == 0) red[tid >> 6] = mx;
  __syncthreads();
  mx = fmaxf(fmaxf(red[0], red[1]), fmaxf(red[2], red[3]));
  __syncthreads();

  float sum = 0.0f;
  for (int i = tid; i < valid; i += 256) sum += __expf(srow[i] - mx);
  for (int off = 32; off; off >>= 1) sum += __shfl_xor(sum, off, 64);
  if ((tid & 63) == 0) red[tid >> 6] = sum;
  __syncthreads();
  sum = red[0] + red[1] + red[2] + red[3];
  float inv = 1.0f / sum;

  for (int i = tid; i < SEQ; i += 256) {
    float v = (i < valid) ? __expf(srow[i] - mx) * inv : 0.0f;
    prow[i] = f2bf(v);
  }
}

extern "C" void kernel_launch(void* const* d_in, const int* in_sizes, int n_in,
                              void* d_out, int out_size, void* d_ws, size_t ws_size,
                              hipStream_t stream) {
  const float* E  = (const float*)d_in[0];
  const float* Wq = (const float*)d_in[1];
  const float* Wk = (const float*)d_in[2];
  const float* Wv = (const float*)d_in[3];
  float* out = (float*)d_out;

  char* ws = (char*)d_ws;
  size_t off = 0;
  auto alloc = [&](size_t bytes) {
    void* p = ws + off;
    off += (bytes + 255) & ~(size_t)255;
    return p;
  };
  const size_t M_ALL = (size_t)BSZ * SEQ;
  unsigned short* Ebf  = (unsigned short*)alloc(M_ALL * DIM * 2);
  unsigned short* WtQK = (unsigned short*)alloc((size_t)2 * DIM * DIM * 2);
  unsigned short* WtV  = (unsigned short*)alloc((size_t)DIM * DIM * 2);
  unsigned short* QK   = (unsigned short*)alloc(M_ALL * 2 * DIM * 2);
  unsigned short* Vt   = (unsigned short*)alloc((size_t)DIM * M_ALL * 2);
  float*          Sc   = (float*)alloc((size_t)BSZ * SEQ * SEQ * 4);
  unsigned short* Pr   = (unsigned short*)alloc((size_t)BSZ * SEQ * SEQ * 2);

  int nE = (int)(M_ALL * DIM);
  cast_e<<<dim3(nE / (256 * 4)), dim3(256), 0, stream>>>(E, Ebf, nE);
  transpose_w<<<dim3(32, 32, 3), dim3(32, 8), 0, stream>>>(Wq, Wk, Wv, WtQK, WtV);

  gemm_nt<unsigned short, 0><<<dim3(16, 64, 1), dim3(256), 0, stream>>>(
      Ebf, DIM, 0, WtQK, DIM, 0, QK, 2 * DIM, 0, DIM, 1.0f);

  gemm_nt<unsigned short, 0><<<dim3(64, 8, 1), dim3(256), 0, stream>>>(
      WtV, DIM, 0, Ebf, DIM, 0, Vt, (int)M_ALL, 0, DIM, 1.0f);

  gemm_nt<float, 1><<<dim3(16, 16, BSZ), dim3(256), 0, stream>>>(
      QK, 2 * DIM, (long long)SEQ * 2 * DIM,
      QK + DIM, 2 * DIM, (long long)SEQ * 2 * DIM,
      Sc, SEQ, (long long)SEQ * SEQ,
      DIM, 0.03125f);

  softmax_causal<<<dim3(SEQ, BSZ), dim3(256), 0, stream>>>(Sc, Pr);

  gemm_nt<float, 2><<<dim3(8, 16, BSZ), dim3(256), 0, stream>>>(
      Pr, SEQ, (long long)SEQ * SEQ,
      Vt, (int)M_ALL, (long long)SEQ,
      out, DIM, (long long)SEQ * DIM,
      SEQ, 1.0f);
}